// Round 1
// 486.679 us; speedup vs baseline: 1.0556x; 1.0556x over previous
//
#include <hip/hip_runtime.h>
#include <math.h>

// GCN 2-layer, f32 in/out. N=100000, E=3200000, F_in=512, H=16, C=7.
// Round 7: round-6 structure, with k_gemm1 rewritten as 16-lane/row cooperative
// GEMM (4 rows per lane-group, k split across lanes):
//   - grid 1563 blocks (vs 196) -> occupancy 7.8% -> ~50%
//   - 256B-contiguous x reads per row-segment -> full line use (FETCH -38%)
//   - W1 transposed in LDS (stride 516) -> conflict-free ds_read_b128,
//     4x register reuse across rows
//   - reduce-and-transpose shuffle: lane l ends with feature l

#define F_IN 512
#define HID  16
#define NCLS 7
#define NCHUNK 256
#define BK 64         // nodes per bucket
#define NBMAX 1600    // >= nb = ceil(N/64) = 1563
#define CAP 3072      // LDS edge capacity in k_b (mean 2048, +22 sigma)
#define WT_STRIDE 516 // padded k-stride of transposed W1 in LDS

static __device__ __forceinline__ float bf2f(unsigned short u) {
    union { unsigned int i; float f; } v; v.i = ((unsigned int)u) << 16; return v.f;
}
static __device__ __forceinline__ unsigned short f2bf(float f) {
    union { float f; unsigned int u; } v; v.f = f;
    unsigned int b = v.u;
    return (unsigned short)((b + 0x7FFFu + ((b >> 16) & 1u)) >> 16);  // RNE
}

// ---- A1: per-chunk histogram over buckets (dst>>6) ----
__global__ __launch_bounds__(256) void k_a1(const int* __restrict__ ei, int E, int perChunk,
                                            int nb, int* __restrict__ bh) {
    __shared__ int hist[NBMAX];
    for (int t = threadIdx.x; t < nb; t += 256) hist[t] = 0;
    __syncthreads();
    const int* dst = ei + E;
    int c = blockIdx.x;
    int s0 = c * perChunk;
    int s1 = min(s0 + perChunk, E);
    for (int e = s0 + threadIdx.x; e < s1; e += 256)
        atomicAdd(&hist[dst[e] >> 6], 1);
    __syncthreads();
    for (int t = threadIdx.x; t < nb; t += 256) bh[(size_t)c * nb + t] = hist[t];
}

// ---- A2a: per-bucket exclusive scan across the 256 chunks (in place) + total ----
__global__ __launch_bounds__(256) void k_a2a(int* __restrict__ bh, int nb,
                                             int* __restrict__ Tb) {
    __shared__ int sd[256];
    int b = blockIdx.x, tid = threadIdx.x;
    int v = bh[(size_t)tid * nb + b];
    sd[tid] = v;
    __syncthreads();
    for (int off = 1; off < 256; off <<= 1) {
        int t = (tid >= off) ? sd[tid - off] : 0;
        __syncthreads();
        sd[tid] += t;
        __syncthreads();
    }
    bh[(size_t)tid * nb + b] = sd[tid] - v;
    if (tid == 255) Tb[b] = sd[255];
}

// ---- A2b: exclusive scan of bucket totals -> bucket bases ----
__global__ __launch_bounds__(256) void k_a2b(const int* __restrict__ Tb, int nb,
                                             int* __restrict__ Bb) {
    __shared__ int sd[256];
    int tid = threadIdx.x;
    int carry = 0;
    for (int base = 0; base < nb; base += 256) {
        int v = (base + tid < nb) ? Tb[base + tid] : 0;
        sd[tid] = v;
        __syncthreads();
        for (int off = 1; off < 256; off <<= 1) {
            int t = (tid >= off) ? sd[tid - off] : 0;
            __syncthreads();
            sd[tid] += t;
            __syncthreads();
        }
        if (base + tid < nb) Bb[base + tid] = carry + sd[tid] - v;
        carry += sd[255];
        __syncthreads();
    }
}

// ---- A3: deterministic partition scatter, packed (dl<<20)|src ----
__global__ __launch_bounds__(256) void k_a3(const int* __restrict__ ei, int E, int perChunk,
                                            int nb, const int* __restrict__ bh,
                                            const int* __restrict__ Bb,
                                            unsigned* __restrict__ part) {
    __shared__ int cur[NBMAX];
    __shared__ int baseL[NBMAX];
    int c = blockIdx.x;
    for (int t = threadIdx.x; t < nb; t += 256) {
        cur[t] = 0;
        baseL[t] = Bb[t] + bh[(size_t)c * nb + t];
    }
    __syncthreads();
    const int* src = ei;
    const int* dst = ei + E;
    int s0 = c * perChunk;
    int s1 = min(s0 + perChunk, E);
    for (int e = s0 + threadIdx.x; e < s1; e += 256) {
        int s = src[e], d = dst[e];
        int b = d >> 6;
        int r = atomicAdd(&cur[b], 1);
        part[baseL[b] + r] = ((unsigned)(d & (BK - 1)) << 20) | (unsigned)s;
    }
}

// ---- B: per-bucket counting sort -> csr (sorted by dst), cnt, offs, dinv ----
__global__ __launch_bounds__(256) void k_b(const unsigned* __restrict__ part,
                                           const int* __restrict__ Tb,
                                           const int* __restrict__ Bb,
                                           int* __restrict__ csr, int* __restrict__ cnt,
                                           int* __restrict__ offs, float* __restrict__ dinv,
                                           int N) {
    __shared__ unsigned eL[CAP];
    __shared__ int hist[BK], sd[BK], cur[BK];
    int b = blockIdx.x, tid = threadIdx.x;
    int base = Bb[b], ct = Tb[b];
    if (tid < BK) hist[tid] = 0;
    __syncthreads();
    for (int k = tid; k < ct; k += 256) {
        unsigned v = part[base + k];
        if (k < CAP) eL[k] = v;
        atomicAdd(&hist[v >> 20], 1);
    }
    __syncthreads();
    if (tid < BK) sd[tid] = hist[tid];
    __syncthreads();
    for (int off = 1; off < BK; off <<= 1) {
        int t = 0;
        if (tid < BK && tid >= off) t = sd[tid - off];
        __syncthreads();
        if (tid < BK) sd[tid] += t;
        __syncthreads();
    }
    if (tid < BK) {
        int h = hist[tid];
        int ex = sd[tid] - h;
        cur[tid] = ex;
        int node = b * BK + tid;
        if (node < N) {
            cnt[node] = h;
            offs[node] = base + ex;
            dinv[node] = rsqrtf((float)h + 1.0f);
        }
    }
    __syncthreads();
    for (int k = tid; k < ct; k += 256) {
        unsigned v = (k < CAP) ? eL[k] : part[base + k];
        int dl = (int)(v >> 20);
        int r = atomicAdd(&cur[dl], 1);
        csr[base + r] = (int)(v & 0xFFFFFu);
    }
}

// ---- GEMM1: hs1b[i][:] = bf16( dinv[i] * (x[i,:] @ W1) ) ----
// 16 lanes/row, 4 rows per lane-group (k split across lanes, W reused 4x).
// W1 staged transposed in LDS: wlT[j][k], stride 516 (conflict-free b128 reads).
__global__ __launch_bounds__(256) void k_gemm1(const float* __restrict__ x,
                                               const float* __restrict__ W1,
                                               const float* __restrict__ dinv,
                                               unsigned short* __restrict__ hs1b,
                                               int N) {
    __shared__ float wlT[HID * WT_STRIDE];  // 33 KB
    {
        // stage transposed: t -> j = t&15, k = (t>>4) + 16*it (coalesced reads,
        // 2-way write aliasing only: bank = (4j + k) & 31)
        int j = threadIdx.x & 15;
        int k0 = threadIdx.x >> 4;
        for (int it = 0; it < F_IN / 16; ++it) {
            int k = k0 + 16 * it;
            wlT[j * WT_STRIDE + k] = W1[k * HID + j];
        }
    }
    __syncthreads();

    int lane = threadIdx.x & 15;
    int g = threadIdx.x >> 4;                 // lane-group 0..15
    int rbase = blockIdx.x * 64 + g * 4;      // 4 rows per group

    const float* xp0 = x + (size_t)(rbase + 0 < N ? rbase + 0 : 0) * F_IN + 4 * lane;
    const float* xp1 = x + (size_t)(rbase + 1 < N ? rbase + 1 : 0) * F_IN + 4 * lane;
    const float* xp2 = x + (size_t)(rbase + 2 < N ? rbase + 2 : 0) * F_IN + 4 * lane;
    const float* xp3 = x + (size_t)(rbase + 3 < N ? rbase + 3 : 0) * F_IN + 4 * lane;

    float acc[4][16];
#pragma unroll
    for (int r = 0; r < 4; ++r)
#pragma unroll
        for (int j = 0; j < 16; ++j) acc[r][j] = 0.0f;

#pragma unroll 2
    for (int p = 0; p < 8; ++p) {
        float4 a0 = *(const float4*)(xp0 + 64 * p);
        float4 a1 = *(const float4*)(xp1 + 64 * p);
        float4 a2 = *(const float4*)(xp2 + 64 * p);
        float4 a3 = *(const float4*)(xp3 + 64 * p);
        const float* wb = &wlT[64 * p + 4 * lane];
#pragma unroll
        for (int j = 0; j < 16; ++j) {
            float4 w4 = *(const float4*)(wb + (size_t)j * WT_STRIDE);
            acc[0][j] = fmaf(a0.x, w4.x, fmaf(a0.y, w4.y, fmaf(a0.z, w4.z, fmaf(a0.w, w4.w, acc[0][j]))));
            acc[1][j] = fmaf(a1.x, w4.x, fmaf(a1.y, w4.y, fmaf(a1.z, w4.z, fmaf(a1.w, w4.w, acc[1][j]))));
            acc[2][j] = fmaf(a2.x, w4.x, fmaf(a2.y, w4.y, fmaf(a2.z, w4.z, fmaf(a2.w, w4.w, acc[2][j]))));
            acc[3][j] = fmaf(a3.x, w4.x, fmaf(a3.y, w4.y, fmaf(a3.z, w4.z, fmaf(a3.w, w4.w, acc[3][j]))));
        }
    }

    // reduce-and-transpose across the 16 lanes: lane l ends with feature j=l.
    bool b8 = (lane & 8) != 0, b4 = (lane & 4) != 0, b2 = (lane & 2) != 0, b1 = (lane & 1) != 0;
#pragma unroll
    for (int r = 0; r < 4; ++r) {
#pragma unroll
        for (int j = 0; j < 8; ++j) {
            float lo = acc[r][j], hi = acc[r][j + 8];
            float keep = b8 ? hi : lo;
            float send = b8 ? lo : hi;
            acc[r][j] = keep + __shfl_xor(send, 8, 16);
        }
#pragma unroll
        for (int j = 0; j < 4; ++j) {
            float lo = acc[r][j], hi = acc[r][j + 4];
            float keep = b4 ? hi : lo;
            float send = b4 ? lo : hi;
            acc[r][j] = keep + __shfl_xor(send, 4, 16);
        }
#pragma unroll
        for (int j = 0; j < 2; ++j) {
            float lo = acc[r][j], hi = acc[r][j + 2];
            float keep = b2 ? hi : lo;
            float send = b2 ? lo : hi;
            acc[r][j] = keep + __shfl_xor(send, 2, 16);
        }
        {
            float lo = acc[r][0], hi = acc[r][1];
            float keep = b1 ? hi : lo;
            float send = b1 ? lo : hi;
            acc[r][0] = keep + __shfl_xor(send, 1, 16);
        }
        int row = rbase + r;
        if (row < N)
            hs1b[(size_t)row * HID + lane] = f2bf(dinv[row] * acc[r][0]);
    }
}

// ---- AGG1: CSR register-accum gather + b1 + relu + @W2 + *dinv -> hs2 (f32) ----
// 16 lanes/node; 4-edge unroll for 4 outstanding 32B row gathers.
__global__ __launch_bounds__(256) void k_agg1(const int* __restrict__ csr,
                                              const int* __restrict__ offs,
                                              const int* __restrict__ cnt,
                                              const float* __restrict__ dinv,
                                              const unsigned short* __restrict__ hs1b,
                                              const float* __restrict__ b1,
                                              const float* __restrict__ W2,
                                              float* __restrict__ hs2, int N) {
    int lane = threadIdx.x & 15;
    int i = blockIdx.x * 16 + (threadIdx.x >> 4);
    float w2r[NCLS];
#pragma unroll
    for (int c = 0; c < NCLS; c++) w2r[c] = W2[lane * NCLS + c];
    float b1l = b1[lane];
    if (i >= N) return;  // group-uniform
    int start = offs[i], end = start + cnt[i];
    float acc = bf2f(hs1b[(size_t)i * HID + lane]);  // self-loop (pre-scaled)
    int k = start;
    for (; k + 3 < end; k += 4) {
        int s0 = csr[k], s1 = csr[k + 1], s2 = csr[k + 2], s3 = csr[k + 3];
        float v0 = bf2f(hs1b[(size_t)s0 * HID + lane]);
        float v1 = bf2f(hs1b[(size_t)s1 * HID + lane]);
        float v2 = bf2f(hs1b[(size_t)s2 * HID + lane]);
        float v3 = bf2f(hs1b[(size_t)s3 * HID + lane]);
        acc += (v0 + v1) + (v2 + v3);
    }
    for (; k < end; k++)
        acc += bf2f(hs1b[(size_t)csr[k] * HID + lane]);
    float v = fmaf(dinv[i], acc, b1l);
    float hr = v > 0.0f ? v : 0.0f;
    float dv = dinv[i];
    float res[NCLS];
#pragma unroll
    for (int c = 0; c < NCLS; c++) {
        float t = hr * w2r[c];
#pragma unroll
        for (int w = 8; w >= 1; w >>= 1) t += __shfl_xor(t, w, 16);
        res[c] = t;
    }
    if (lane < NCLS) {
        float o = res[0];
#pragma unroll
        for (int c = 1; c < NCLS; c++) o = (lane == c) ? res[c] : o;
        hs2[(size_t)i * NCLS + lane] = dv * o;
    }
}

// ---- AGG2: CSR register-accum gather + b2 + log_softmax -> out. 8 lanes/node ----
__global__ __launch_bounds__(256) void k_agg2(const int* __restrict__ csr,
                                              const int* __restrict__ offs,
                                              const int* __restrict__ cnt,
                                              const float* __restrict__ dinv,
                                              const float* __restrict__ hs2,
                                              const float* __restrict__ b2,
                                              float* __restrict__ out, int N) {
    int lane = threadIdx.x & 7;
    int i = blockIdx.x * 32 + (threadIdx.x >> 3);
    if (i >= N) return;  // group-uniform
    int cc = lane < NCLS ? lane : NCLS - 1;
    int start = offs[i], end = start + cnt[i];
    float acc = hs2[(size_t)i * NCLS + cc];  // self-loop (pre-scaled)
    int k = start;
    for (; k + 3 < end; k += 4) {
        int s0 = csr[k], s1 = csr[k + 1], s2 = csr[k + 2], s3 = csr[k + 3];
        float v0 = hs2[(size_t)s0 * NCLS + cc];
        float v1 = hs2[(size_t)s1 * NCLS + cc];
        float v2 = hs2[(size_t)s2 * NCLS + cc];
        float v3 = hs2[(size_t)s3 * NCLS + cc];
        acc += (v0 + v1) + (v2 + v3);
    }
    for (; k < end; k++)
        acc += hs2[(size_t)csr[k] * NCLS + cc];
    float v = fmaf(dinv[i], acc, b2[cc]);
    float vm = (lane < NCLS) ? v : -INFINITY;
    float m = vm;
#pragma unroll
    for (int w = 4; w >= 1; w >>= 1) m = fmaxf(m, __shfl_xor(m, w, 8));
    float e = (lane < NCLS) ? expf(v - m) : 0.0f;
    float ssum = e;
#pragma unroll
    for (int w = 4; w >= 1; w >>= 1) ssum += __shfl_xor(ssum, w, 8);
    if (lane < NCLS) out[(size_t)i * NCLS + lane] = v - m - logf(ssum);
}

extern "C" void kernel_launch(void* const* d_in, const int* in_sizes, int n_in,
                              void* d_out, int out_size, void* d_ws, size_t ws_size,
                              hipStream_t stream) {
    const float* x  = (const float*)d_in[0];
    const int*   ei = (const int*)d_in[1];
    const float* W1 = (const float*)d_in[2];
    const float* b1 = (const float*)d_in[3];
    const float* W2 = (const float*)d_in[4];
    const float* b2 = (const float*)d_in[5];
    float* out = (float*)d_out;

    const int N = in_sizes[0] / F_IN;          // 100000
    const int E = in_sizes[1] / 2;             // 3200000
    const int nb = (N + BK - 1) / BK;          // 1563
    const int perChunk = (E + NCHUNK - 1) / NCHUNK;  // 12500

    // ws layout in 4B words, 16B-aligned chunks:
    // [part E][csr E][hs1b 8N(u32)][hs2 7N][dinv N][cnt N][offs N][bh 256*nb][Tb nb][Bb nb]
    unsigned* w = (unsigned*)d_ws;
    auto al4 = [](size_t v) { return (v + 3) & ~(size_t)3; };
    size_t o = 0;
    unsigned*       part = w + o;               o = al4(o + E);
    int*            csr  = (int*)(w + o);       o = al4(o + E);
    unsigned short* hs1b = (unsigned short*)(w + o); o = al4(o + (size_t)N * HID / 2);
    float*          hs2  = (float*)(w + o);     o = al4(o + (size_t)N * NCLS);
    float*          dinv = (float*)(w + o);     o = al4(o + N);
    int*            cnt  = (int*)(w + o);       o = al4(o + N);
    int*            offs = (int*)(w + o);       o = al4(o + (size_t)NCHUNK * nb > 0 ? o + N - N + N : N), o = al4(o);  // keep layout identical
    // NOTE: the line above must match round-6 layout exactly; rewritten plainly:
    o = 0;
    part = w + o;                               o = al4(o + E);
    csr  = (int*)(w + o);                       o = al4(o + E);
    hs1b = (unsigned short*)(w + o);            o = al4(o + (size_t)N * HID / 2);
    hs2  = (float*)(w + o);                     o = al4(o + (size_t)N * NCLS);
    dinv = (float*)(w + o);                     o = al4(o + N);
    cnt  = (int*)(w + o);                       o = al4(o + N);
    offs = (int*)(w + o);                       o = al4(o + N);
    int*            bh   = (int*)(w + o);       o = al4(o + (size_t)NCHUNK * nb);
    int*            Tb   = (int*)(w + o);       o = al4(o + nb);
    int*            Bb   = (int*)(w + o);

    k_a1<<<NCHUNK, 256, 0, stream>>>(ei, E, perChunk, nb, bh);
    k_a2a<<<nb, 256, 0, stream>>>(bh, nb, Tb);
    k_a2b<<<1, 256, 0, stream>>>(Tb, nb, Bb);
    k_a3<<<NCHUNK, 256, 0, stream>>>(ei, E, perChunk, nb, bh, Bb, part);
    k_b<<<nb, 256, 0, stream>>>(part, Tb, Bb, csr, cnt, offs, dinv, N);
    k_gemm1<<<(N + 63) / 64, 256, 0, stream>>>(x, W1, dinv, hs1b, N);
    k_agg1<<<(N + 15) / 16, 256, 0, stream>>>(csr, offs, cnt, dinv, hs1b, b1, W2, hs2, N);
    k_agg2<<<(N + 31) / 32, 256, 0, stream>>>(csr, offs, cnt, dinv, hs2, b2, out, N);
}

// Round 2
// 477.718 us; speedup vs baseline: 1.0754x; 1.0188x over previous
//
#include <hip/hip_runtime.h>
#include <math.h>

// GCN 2-layer, f32 in/out. N=100000, E=3200000, F_in=512, H=16, C=7.
// Round 8: round-7 structure, with the two gather kernels restructured to cut
// VMEM instruction count (they are L2-resident, instruction/latency bound):
//   - k_agg1: 8 lanes/node, paired-bf16 u32 gathers (halves gather insts),
//     csr loads distributed across lanes + __shfl broadcast (8x fewer loads)
//   - k_agg2: hs2 padded to 8 f32/row (aligned 32B gathers), same csr
//     shuffle-broadcast batching
//   - padded hs2 aliases the dead `part` buffer (no workspace growth)

#define F_IN 512
#define HID  16
#define NCLS 7
#define NCHUNK 256
#define BK 64         // nodes per bucket
#define NBMAX 1600    // >= nb = ceil(N/64) = 1563
#define CAP 3072      // LDS edge capacity in k_b (mean 2048, +22 sigma)
#define WT_STRIDE 516 // padded k-stride of transposed W1 in LDS

static __device__ __forceinline__ float bf2f(unsigned short u) {
    union { unsigned int i; float f; } v; v.i = ((unsigned int)u) << 16; return v.f;
}
static __device__ __forceinline__ unsigned short f2bf(float f) {
    union { float f; unsigned int u; } v; v.f = f;
    unsigned int b = v.u;
    return (unsigned short)((b + 0x7FFFu + ((b >> 16) & 1u)) >> 16);  // RNE
}

// ---- A1: per-chunk histogram over buckets (dst>>6) ----
__global__ __launch_bounds__(256) void k_a1(const int* __restrict__ ei, int E, int perChunk,
                                            int nb, int* __restrict__ bh) {
    __shared__ int hist[NBMAX];
    for (int t = threadIdx.x; t < nb; t += 256) hist[t] = 0;
    __syncthreads();
    const int* dst = ei + E;
    int c = blockIdx.x;
    int s0 = c * perChunk;
    int s1 = min(s0 + perChunk, E);
    for (int e = s0 + threadIdx.x; e < s1; e += 256)
        atomicAdd(&hist[dst[e] >> 6], 1);
    __syncthreads();
    for (int t = threadIdx.x; t < nb; t += 256) bh[(size_t)c * nb + t] = hist[t];
}

// ---- A2a: per-bucket exclusive scan across the 256 chunks (in place) + total ----
__global__ __launch_bounds__(256) void k_a2a(int* __restrict__ bh, int nb,
                                             int* __restrict__ Tb) {
    __shared__ int sd[256];
    int b = blockIdx.x, tid = threadIdx.x;
    int v = bh[(size_t)tid * nb + b];
    sd[tid] = v;
    __syncthreads();
    for (int off = 1; off < 256; off <<= 1) {
        int t = (tid >= off) ? sd[tid - off] : 0;
        __syncthreads();
        sd[tid] += t;
        __syncthreads();
    }
    bh[(size_t)tid * nb + b] = sd[tid] - v;
    if (tid == 255) Tb[b] = sd[255];
}

// ---- A2b: exclusive scan of bucket totals -> bucket bases ----
__global__ __launch_bounds__(256) void k_a2b(const int* __restrict__ Tb, int nb,
                                             int* __restrict__ Bb) {
    __shared__ int sd[256];
    int tid = threadIdx.x;
    int carry = 0;
    for (int base = 0; base < nb; base += 256) {
        int v = (base + tid < nb) ? Tb[base + tid] : 0;
        sd[tid] = v;
        __syncthreads();
        for (int off = 1; off < 256; off <<= 1) {
            int t = (tid >= off) ? sd[tid - off] : 0;
            __syncthreads();
            sd[tid] += t;
            __syncthreads();
        }
        if (base + tid < nb) Bb[base + tid] = carry + sd[tid] - v;
        carry += sd[255];
        __syncthreads();
    }
}

// ---- A3: deterministic partition scatter, packed (dl<<20)|src ----
__global__ __launch_bounds__(256) void k_a3(const int* __restrict__ ei, int E, int perChunk,
                                            int nb, const int* __restrict__ bh,
                                            const int* __restrict__ Bb,
                                            unsigned* __restrict__ part) {
    __shared__ int cur[NBMAX];
    __shared__ int baseL[NBMAX];
    int c = blockIdx.x;
    for (int t = threadIdx.x; t < nb; t += 256) {
        cur[t] = 0;
        baseL[t] = Bb[t] + bh[(size_t)c * nb + t];
    }
    __syncthreads();
    const int* src = ei;
    const int* dst = ei + E;
    int s0 = c * perChunk;
    int s1 = min(s0 + perChunk, E);
    for (int e = s0 + threadIdx.x; e < s1; e += 256) {
        int s = src[e], d = dst[e];
        int b = d >> 6;
        int r = atomicAdd(&cur[b], 1);
        part[baseL[b] + r] = ((unsigned)(d & (BK - 1)) << 20) | (unsigned)s;
    }
}

// ---- B: per-bucket counting sort -> csr (sorted by dst), cnt, offs, dinv ----
__global__ __launch_bounds__(256) void k_b(const unsigned* __restrict__ part,
                                           const int* __restrict__ Tb,
                                           const int* __restrict__ Bb,
                                           int* __restrict__ csr, int* __restrict__ cnt,
                                           int* __restrict__ offs, float* __restrict__ dinv,
                                           int N) {
    __shared__ unsigned eL[CAP];
    __shared__ int hist[BK], sd[BK], cur[BK];
    int b = blockIdx.x, tid = threadIdx.x;
    int base = Bb[b], ct = Tb[b];
    if (tid < BK) hist[tid] = 0;
    __syncthreads();
    for (int k = tid; k < ct; k += 256) {
        unsigned v = part[base + k];
        if (k < CAP) eL[k] = v;
        atomicAdd(&hist[v >> 20], 1);
    }
    __syncthreads();
    if (tid < BK) sd[tid] = hist[tid];
    __syncthreads();
    for (int off = 1; off < BK; off <<= 1) {
        int t = 0;
        if (tid < BK && tid >= off) t = sd[tid - off];
        __syncthreads();
        if (tid < BK) sd[tid] += t;
        __syncthreads();
    }
    if (tid < BK) {
        int h = hist[tid];
        int ex = sd[tid] - h;
        cur[tid] = ex;
        int node = b * BK + tid;
        if (node < N) {
            cnt[node] = h;
            offs[node] = base + ex;
            dinv[node] = rsqrtf((float)h + 1.0f);
        }
    }
    __syncthreads();
    for (int k = tid; k < ct; k += 256) {
        unsigned v = (k < CAP) ? eL[k] : part[base + k];
        int dl = (int)(v >> 20);
        int r = atomicAdd(&cur[dl], 1);
        csr[base + r] = (int)(v & 0xFFFFFu);
    }
}

// ---- GEMM1: hs1b[i][:] = bf16( dinv[i] * (x[i,:] @ W1) ) ----
// 16 lanes/row, 4 rows per lane-group (k split across lanes, W reused 4x).
// W1 staged transposed in LDS: wlT[j][k], stride 516 (conflict-free b128 reads).
__global__ __launch_bounds__(256) void k_gemm1(const float* __restrict__ x,
                                               const float* __restrict__ W1,
                                               const float* __restrict__ dinv,
                                               unsigned short* __restrict__ hs1b,
                                               int N) {
    __shared__ float wlT[HID * WT_STRIDE];  // 33 KB
    {
        int j = threadIdx.x & 15;
        int k0 = threadIdx.x >> 4;
        for (int it = 0; it < F_IN / 16; ++it) {
            int k = k0 + 16 * it;
            wlT[j * WT_STRIDE + k] = W1[k * HID + j];
        }
    }
    __syncthreads();

    int lane = threadIdx.x & 15;
    int g = threadIdx.x >> 4;                 // lane-group 0..15
    int rbase = blockIdx.x * 64 + g * 4;      // 4 rows per group

    const float* xp0 = x + (size_t)(rbase + 0 < N ? rbase + 0 : 0) * F_IN + 4 * lane;
    const float* xp1 = x + (size_t)(rbase + 1 < N ? rbase + 1 : 0) * F_IN + 4 * lane;
    const float* xp2 = x + (size_t)(rbase + 2 < N ? rbase + 2 : 0) * F_IN + 4 * lane;
    const float* xp3 = x + (size_t)(rbase + 3 < N ? rbase + 3 : 0) * F_IN + 4 * lane;

    float acc[4][16];
#pragma unroll
    for (int r = 0; r < 4; ++r)
#pragma unroll
        for (int j = 0; j < 16; ++j) acc[r][j] = 0.0f;

#pragma unroll 2
    for (int p = 0; p < 8; ++p) {
        float4 a0 = *(const float4*)(xp0 + 64 * p);
        float4 a1 = *(const float4*)(xp1 + 64 * p);
        float4 a2 = *(const float4*)(xp2 + 64 * p);
        float4 a3 = *(const float4*)(xp3 + 64 * p);
        const float* wb = &wlT[64 * p + 4 * lane];
#pragma unroll
        for (int j = 0; j < 16; ++j) {
            float4 w4 = *(const float4*)(wb + (size_t)j * WT_STRIDE);
            acc[0][j] = fmaf(a0.x, w4.x, fmaf(a0.y, w4.y, fmaf(a0.z, w4.z, fmaf(a0.w, w4.w, acc[0][j]))));
            acc[1][j] = fmaf(a1.x, w4.x, fmaf(a1.y, w4.y, fmaf(a1.z, w4.z, fmaf(a1.w, w4.w, acc[1][j]))));
            acc[2][j] = fmaf(a2.x, w4.x, fmaf(a2.y, w4.y, fmaf(a2.z, w4.z, fmaf(a2.w, w4.w, acc[2][j]))));
            acc[3][j] = fmaf(a3.x, w4.x, fmaf(a3.y, w4.y, fmaf(a3.z, w4.z, fmaf(a3.w, w4.w, acc[3][j]))));
        }
    }

    // reduce-and-transpose across the 16 lanes: lane l ends with feature j=l.
    bool b8 = (lane & 8) != 0, b4 = (lane & 4) != 0, b2 = (lane & 2) != 0, b1 = (lane & 1) != 0;
#pragma unroll
    for (int r = 0; r < 4; ++r) {
#pragma unroll
        for (int j = 0; j < 8; ++j) {
            float lo = acc[r][j], hi = acc[r][j + 8];
            float keep = b8 ? hi : lo;
            float send = b8 ? lo : hi;
            acc[r][j] = keep + __shfl_xor(send, 8, 16);
        }
#pragma unroll
        for (int j = 0; j < 4; ++j) {
            float lo = acc[r][j], hi = acc[r][j + 4];
            float keep = b4 ? hi : lo;
            float send = b4 ? lo : hi;
            acc[r][j] = keep + __shfl_xor(send, 4, 16);
        }
#pragma unroll
        for (int j = 0; j < 2; ++j) {
            float lo = acc[r][j], hi = acc[r][j + 2];
            float keep = b2 ? hi : lo;
            float send = b2 ? lo : hi;
            acc[r][j] = keep + __shfl_xor(send, 2, 16);
        }
        {
            float lo = acc[r][0], hi = acc[r][1];
            float keep = b1 ? hi : lo;
            float send = b1 ? lo : hi;
            acc[r][0] = keep + __shfl_xor(send, 1, 16);
        }
        int row = rbase + r;
        if (row < N)
            hs1b[(size_t)row * HID + lane] = f2bf(dinv[row] * acc[r][0]);
    }
}

// ---- AGG1: CSR gather + b1 + relu + @W2 + *dinv -> hs2p (f32, 8/row) ----
// 8 lanes/node, each lane owns features (2l, 2l+1) as one u32 (bf16 pair).
// csr loads distributed across the 8 lanes, broadcast via __shfl.
__global__ __launch_bounds__(256) void k_agg1(const int* __restrict__ csr,
                                              const int* __restrict__ offs,
                                              const int* __restrict__ cnt,
                                              const float* __restrict__ dinv,
                                              const unsigned* __restrict__ hs1u,
                                              const float* __restrict__ b1,
                                              const float* __restrict__ W2,
                                              float* __restrict__ hs2p, int N) {
    int lane = threadIdx.x & 7;
    int i = blockIdx.x * 32 + (threadIdx.x >> 3);
    float w2a[NCLS], w2b[NCLS];
#pragma unroll
    for (int c = 0; c < NCLS; c++) {
        w2a[c] = W2[(2 * lane) * NCLS + c];
        w2b[c] = W2[(2 * lane + 1) * NCLS + c];
    }
    float b1a = b1[2 * lane], b1b = b1[2 * lane + 1];
    if (i >= N) return;  // group-uniform
    int start = offs[i], cn = cnt[i];
    unsigned su = hs1u[(size_t)i * 8 + lane];  // self-loop (pre-scaled)
    float accA = __uint_as_float(su << 16);
    float accB = __uint_as_float(su & 0xffff0000u);
    int full = cn & ~7;
    for (int k = 0; k < full; k += 8) {
        int ev = csr[start + k + lane];
#pragma unroll
        for (int t = 0; t < 8; ++t) {
            int s = __shfl(ev, t, 8);
            unsigned u = hs1u[(size_t)s * 8 + lane];
            accA += __uint_as_float(u << 16);
            accB += __uint_as_float(u & 0xffff0000u);
        }
    }
    int rem = cn - full;
    if (rem) {
        int ev = (lane < rem) ? csr[start + full + lane] : 0;
        for (int t = 0; t < rem; ++t) {
            int s = __shfl(ev, t, 8);
            unsigned u = hs1u[(size_t)s * 8 + lane];
            accA += __uint_as_float(u << 16);
            accB += __uint_as_float(u & 0xffff0000u);
        }
    }
    float dv = dinv[i];
    float vA = fmaf(dv, accA, b1a);
    float vB = fmaf(dv, accB, b1b);
    float hA = vA > 0.0f ? vA : 0.0f;
    float hB = vB > 0.0f ? vB : 0.0f;
    float res[NCLS];
#pragma unroll
    for (int c = 0; c < NCLS; c++) {
        float t = fmaf(hA, w2a[c], hB * w2b[c]);
#pragma unroll
        for (int w = 4; w >= 1; w >>= 1) t += __shfl_xor(t, w, 8);
        res[c] = t;
    }
    float o = res[0];
#pragma unroll
    for (int c = 1; c < NCLS; c++) o = (lane == c) ? res[c] : o;
    hs2p[(size_t)i * 8 + lane] = dv * o;  // lane 7 writes dv*res[0] (pad, unused)
}

// ---- AGG2: CSR gather (8 f32/row padded) + b2 + log_softmax -> out ----
// 8 lanes/node; csr loads distributed + __shfl broadcast; aligned 32B rows.
__global__ __launch_bounds__(256) void k_agg2(const int* __restrict__ csr,
                                              const int* __restrict__ offs,
                                              const int* __restrict__ cnt,
                                              const float* __restrict__ dinv,
                                              const float* __restrict__ hs2p,
                                              const float* __restrict__ b2,
                                              float* __restrict__ out, int N) {
    int lane = threadIdx.x & 7;
    int i = blockIdx.x * 32 + (threadIdx.x >> 3);
    if (i >= N) return;  // group-uniform
    int start = offs[i], cn = cnt[i];
    float acc = hs2p[(size_t)i * 8 + lane];  // self-loop (pre-scaled)
    int full = cn & ~7;
    for (int k = 0; k < full; k += 8) {
        int ev = csr[start + k + lane];
#pragma unroll
        for (int t = 0; t < 8; ++t) {
            int s = __shfl(ev, t, 8);
            acc += hs2p[(size_t)s * 8 + lane];
        }
    }
    int rem = cn - full;
    if (rem) {
        int ev = (lane < rem) ? csr[start + full + lane] : 0;
        for (int t = 0; t < rem; ++t) {
            int s = __shfl(ev, t, 8);
            acc += hs2p[(size_t)s * 8 + lane];
        }
    }
    int cc = lane < NCLS ? lane : NCLS - 1;
    float v = fmaf(dinv[i], acc, b2[cc]);
    float vm = (lane < NCLS) ? v : -INFINITY;
    float m = vm;
#pragma unroll
    for (int w = 4; w >= 1; w >>= 1) m = fmaxf(m, __shfl_xor(m, w, 8));
    float e = (lane < NCLS) ? expf(v - m) : 0.0f;
    float ssum = e;
#pragma unroll
    for (int w = 4; w >= 1; w >>= 1) ssum += __shfl_xor(ssum, w, 8);
    if (lane < NCLS) out[(size_t)i * NCLS + lane] = v - m - logf(ssum);
}

extern "C" void kernel_launch(void* const* d_in, const int* in_sizes, int n_in,
                              void* d_out, int out_size, void* d_ws, size_t ws_size,
                              hipStream_t stream) {
    const float* x  = (const float*)d_in[0];
    const int*   ei = (const int*)d_in[1];
    const float* W1 = (const float*)d_in[2];
    const float* b1 = (const float*)d_in[3];
    const float* W2 = (const float*)d_in[4];
    const float* b2 = (const float*)d_in[5];
    float* out = (float*)d_out;

    const int N = in_sizes[0] / F_IN;          // 100000
    const int E = in_sizes[1] / 2;             // 3200000
    const int nb = (N + BK - 1) / BK;          // 1563
    const int perChunk = (E + NCHUNK - 1) / NCHUNK;  // 12500

    // ws layout in 4B words, 16B-aligned chunks:
    // [part E | hs2p 8N (aliased; part dead after k_b)][csr E][hs1b 8N(u32)]
    // [dinv N][cnt N][offs N][bh 256*nb][Tb nb][Bb nb]
    unsigned* w = (unsigned*)d_ws;
    auto al4 = [](size_t v) { return (v + 3) & ~(size_t)3; };
    size_t o = 0;
    unsigned*       part = w + o;
    float*          hs2p = (float*)(w + o);     o = al4(o + E);
    int*            csr  = (int*)(w + o);       o = al4(o + E);
    unsigned short* hs1b = (unsigned short*)(w + o); o = al4(o + (size_t)N * HID / 2);
    float*          dinv = (float*)(w + o);     o = al4(o + N);
    int*            cnt  = (int*)(w + o);       o = al4(o + N);
    int*            offs = (int*)(w + o);       o = al4(o + N);
    int*            bh   = (int*)(w + o);       o = al4(o + (size_t)NCHUNK * nb);
    int*            Tb   = (int*)(w + o);       o = al4(o + nb);
    int*            Bb   = (int*)(w + o);

    k_a1<<<NCHUNK, 256, 0, stream>>>(ei, E, perChunk, nb, bh);
    k_a2a<<<nb, 256, 0, stream>>>(bh, nb, Tb);
    k_a2b<<<1, 256, 0, stream>>>(Tb, nb, Bb);
    k_a3<<<NCHUNK, 256, 0, stream>>>(ei, E, perChunk, nb, bh, Bb, part);
    k_b<<<nb, 256, 0, stream>>>(part, Tb, Bb, csr, cnt, offs, dinv, N);
    k_gemm1<<<(N + 63) / 64, 256, 0, stream>>>(x, W1, dinv, hs1b, N);
    k_agg1<<<(N + 31) / 32, 256, 0, stream>>>(csr, offs, cnt, dinv,
                                              (const unsigned*)hs1b, b1, W2, hs2p, N);
    k_agg2<<<(N + 31) / 32, 256, 0, stream>>>(csr, offs, cnt, dinv, hs2p, b2, out, N);
}

// Round 3
// 455.342 us; speedup vs baseline: 1.1283x; 1.0491x over previous
//
#include <hip/hip_runtime.h>
#include <math.h>

// GCN 2-layer, f32 in/out. N=100000, E=3200000, F_in=512, H=16, C=7.
// Round 9: round-8 structure with BK 64 -> 256 (nb=391):
//   - k_a3 scatter runs grow 32B -> 128B per (chunk,bucket): kills the
//     partial-line RMW write amplification on the 12.8MB part array
//   - k_b: 256-node buckets (~8192 edges), LDS staging 36KB (CAP 9216),
//     hist/scan arrays exactly 256-wide; csr scatter stays in a 32KB
//     L2-resident region
//   - gemm1 / agg1 / agg2 unchanged from round 8

#define F_IN 512
#define HID  16
#define NCLS 7
#define NCHUNK 256
#define BK 256        // nodes per bucket
#define NBMAX 400     // >= nb = ceil(N/256) = 391
#define CAP 9216      // LDS edge capacity in k_b (mean 8192, +11 sigma)
#define WT_STRIDE 516 // padded k-stride of transposed W1 in LDS

static __device__ __forceinline__ float bf2f(unsigned short u) {
    union { unsigned int i; float f; } v; v.i = ((unsigned int)u) << 16; return v.f;
}
static __device__ __forceinline__ unsigned short f2bf(float f) {
    union { float f; unsigned int u; } v; v.f = f;
    unsigned int b = v.u;
    return (unsigned short)((b + 0x7FFFu + ((b >> 16) & 1u)) >> 16);  // RNE
}

// ---- A1: per-chunk histogram over buckets (dst>>8) ----
__global__ __launch_bounds__(256) void k_a1(const int* __restrict__ ei, int E, int perChunk,
                                            int nb, int* __restrict__ bh) {
    __shared__ int hist[NBMAX];
    for (int t = threadIdx.x; t < nb; t += 256) hist[t] = 0;
    __syncthreads();
    const int* dst = ei + E;
    int c = blockIdx.x;
    int s0 = c * perChunk;
    int s1 = min(s0 + perChunk, E);
    for (int e = s0 + threadIdx.x; e < s1; e += 256)
        atomicAdd(&hist[dst[e] >> 8], 1);
    __syncthreads();
    for (int t = threadIdx.x; t < nb; t += 256) bh[(size_t)c * nb + t] = hist[t];
}

// ---- A2a: per-bucket exclusive scan across the 256 chunks (in place) + total ----
__global__ __launch_bounds__(256) void k_a2a(int* __restrict__ bh, int nb,
                                             int* __restrict__ Tb) {
    __shared__ int sd[256];
    int b = blockIdx.x, tid = threadIdx.x;
    int v = bh[(size_t)tid * nb + b];
    sd[tid] = v;
    __syncthreads();
    for (int off = 1; off < 256; off <<= 1) {
        int t = (tid >= off) ? sd[tid - off] : 0;
        __syncthreads();
        sd[tid] += t;
        __syncthreads();
    }
    bh[(size_t)tid * nb + b] = sd[tid] - v;
    if (tid == 255) Tb[b] = sd[255];
}

// ---- A2b: exclusive scan of bucket totals -> bucket bases ----
__global__ __launch_bounds__(256) void k_a2b(const int* __restrict__ Tb, int nb,
                                             int* __restrict__ Bb) {
    __shared__ int sd[256];
    int tid = threadIdx.x;
    int carry = 0;
    for (int base = 0; base < nb; base += 256) {
        int v = (base + tid < nb) ? Tb[base + tid] : 0;
        sd[tid] = v;
        __syncthreads();
        for (int off = 1; off < 256; off <<= 1) {
            int t = (tid >= off) ? sd[tid - off] : 0;
            __syncthreads();
            sd[tid] += t;
            __syncthreads();
        }
        if (base + tid < nb) Bb[base + tid] = carry + sd[tid] - v;
        carry += sd[255];
        __syncthreads();
    }
}

// ---- A3: deterministic partition scatter, packed (dl<<20)|src ----
__global__ __launch_bounds__(256) void k_a3(const int* __restrict__ ei, int E, int perChunk,
                                            int nb, const int* __restrict__ bh,
                                            const int* __restrict__ Bb,
                                            unsigned* __restrict__ part) {
    __shared__ int cur[NBMAX];
    __shared__ int baseL[NBMAX];
    int c = blockIdx.x;
    for (int t = threadIdx.x; t < nb; t += 256) {
        cur[t] = 0;
        baseL[t] = Bb[t] + bh[(size_t)c * nb + t];
    }
    __syncthreads();
    const int* src = ei;
    const int* dst = ei + E;
    int s0 = c * perChunk;
    int s1 = min(s0 + perChunk, E);
    for (int e = s0 + threadIdx.x; e < s1; e += 256) {
        int s = src[e], d = dst[e];
        int b = d >> 8;
        int r = atomicAdd(&cur[b], 1);
        part[baseL[b] + r] = ((unsigned)(d & (BK - 1)) << 20) | (unsigned)s;
    }
}

// ---- B: per-bucket counting sort -> csr (sorted by dst), cnt, offs, dinv ----
__global__ __launch_bounds__(256) void k_b(const unsigned* __restrict__ part,
                                           const int* __restrict__ Tb,
                                           const int* __restrict__ Bb,
                                           int* __restrict__ csr, int* __restrict__ cnt,
                                           int* __restrict__ offs, float* __restrict__ dinv,
                                           int N) {
    __shared__ unsigned eL[CAP];
    __shared__ int hist[BK], sd[BK], cur[BK];
    int b = blockIdx.x, tid = threadIdx.x;
    int base = Bb[b], ct = Tb[b];
    hist[tid] = 0;
    __syncthreads();
    for (int k = tid; k < ct; k += 256) {
        unsigned v = part[base + k];
        if (k < CAP) eL[k] = v;
        atomicAdd(&hist[v >> 20], 1);
    }
    __syncthreads();
    sd[tid] = hist[tid];
    __syncthreads();
    for (int off = 1; off < BK; off <<= 1) {
        int t = (tid >= off) ? sd[tid - off] : 0;
        __syncthreads();
        sd[tid] += t;
        __syncthreads();
    }
    {
        int h = hist[tid];
        int ex = sd[tid] - h;
        cur[tid] = ex;
        int node = b * BK + tid;
        if (node < N) {
            cnt[node] = h;
            offs[node] = base + ex;
            dinv[node] = rsqrtf((float)h + 1.0f);
        }
    }
    __syncthreads();
    for (int k = tid; k < ct; k += 256) {
        unsigned v = (k < CAP) ? eL[k] : part[base + k];
        int dl = (int)(v >> 20);
        int r = atomicAdd(&cur[dl], 1);
        csr[base + r] = (int)(v & 0xFFFFFu);
    }
}

// ---- GEMM1: hs1b[i][:] = bf16( dinv[i] * (x[i,:] @ W1) ) ----
// 16 lanes/row, 4 rows per lane-group (k split across lanes, W reused 4x).
// W1 staged transposed in LDS: wlT[j][k], stride 516 (conflict-free b128 reads).
__global__ __launch_bounds__(256) void k_gemm1(const float* __restrict__ x,
                                               const float* __restrict__ W1,
                                               const float* __restrict__ dinv,
                                               unsigned short* __restrict__ hs1b,
                                               int N) {
    __shared__ float wlT[HID * WT_STRIDE];  // 33 KB
    {
        int j = threadIdx.x & 15;
        int k0 = threadIdx.x >> 4;
        for (int it = 0; it < F_IN / 16; ++it) {
            int k = k0 + 16 * it;
            wlT[j * WT_STRIDE + k] = W1[k * HID + j];
        }
    }
    __syncthreads();

    int lane = threadIdx.x & 15;
    int g = threadIdx.x >> 4;                 // lane-group 0..15
    int rbase = blockIdx.x * 64 + g * 4;      // 4 rows per group

    const float* xp0 = x + (size_t)(rbase + 0 < N ? rbase + 0 : 0) * F_IN + 4 * lane;
    const float* xp1 = x + (size_t)(rbase + 1 < N ? rbase + 1 : 0) * F_IN + 4 * lane;
    const float* xp2 = x + (size_t)(rbase + 2 < N ? rbase + 2 : 0) * F_IN + 4 * lane;
    const float* xp3 = x + (size_t)(rbase + 3 < N ? rbase + 3 : 0) * F_IN + 4 * lane;

    float acc[4][16];
#pragma unroll
    for (int r = 0; r < 4; ++r)
#pragma unroll
        for (int j = 0; j < 16; ++j) acc[r][j] = 0.0f;

#pragma unroll 2
    for (int p = 0; p < 8; ++p) {
        float4 a0 = *(const float4*)(xp0 + 64 * p);
        float4 a1 = *(const float4*)(xp1 + 64 * p);
        float4 a2 = *(const float4*)(xp2 + 64 * p);
        float4 a3 = *(const float4*)(xp3 + 64 * p);
        const float* wb = &wlT[64 * p + 4 * lane];
#pragma unroll
        for (int j = 0; j < 16; ++j) {
            float4 w4 = *(const float4*)(wb + (size_t)j * WT_STRIDE);
            acc[0][j] = fmaf(a0.x, w4.x, fmaf(a0.y, w4.y, fmaf(a0.z, w4.z, fmaf(a0.w, w4.w, acc[0][j]))));
            acc[1][j] = fmaf(a1.x, w4.x, fmaf(a1.y, w4.y, fmaf(a1.z, w4.z, fmaf(a1.w, w4.w, acc[1][j]))));
            acc[2][j] = fmaf(a2.x, w4.x, fmaf(a2.y, w4.y, fmaf(a2.z, w4.z, fmaf(a2.w, w4.w, acc[2][j]))));
            acc[3][j] = fmaf(a3.x, w4.x, fmaf(a3.y, w4.y, fmaf(a3.z, w4.z, fmaf(a3.w, w4.w, acc[3][j]))));
        }
    }

    // reduce-and-transpose across the 16 lanes: lane l ends with feature j=l.
    bool b8 = (lane & 8) != 0, b4 = (lane & 4) != 0, b2 = (lane & 2) != 0, b1 = (lane & 1) != 0;
#pragma unroll
    for (int r = 0; r < 4; ++r) {
#pragma unroll
        for (int j = 0; j < 8; ++j) {
            float lo = acc[r][j], hi = acc[r][j + 8];
            float keep = b8 ? hi : lo;
            float send = b8 ? lo : hi;
            acc[r][j] = keep + __shfl_xor(send, 8, 16);
        }
#pragma unroll
        for (int j = 0; j < 4; ++j) {
            float lo = acc[r][j], hi = acc[r][j + 4];
            float keep = b4 ? hi : lo;
            float send = b4 ? lo : hi;
            acc[r][j] = keep + __shfl_xor(send, 4, 16);
        }
#pragma unroll
        for (int j = 0; j < 2; ++j) {
            float lo = acc[r][j], hi = acc[r][j + 2];
            float keep = b2 ? hi : lo;
            float send = b2 ? lo : hi;
            acc[r][j] = keep + __shfl_xor(send, 2, 16);
        }
        {
            float lo = acc[r][0], hi = acc[r][1];
            float keep = b1 ? hi : lo;
            float send = b1 ? lo : hi;
            acc[r][0] = keep + __shfl_xor(send, 1, 16);
        }
        int row = rbase + r;
        if (row < N)
            hs1b[(size_t)row * HID + lane] = f2bf(dinv[row] * acc[r][0]);
    }
}

// ---- AGG1: CSR gather + b1 + relu + @W2 + *dinv -> hs2p (f32, 8/row) ----
// 8 lanes/node, each lane owns features (2l, 2l+1) as one u32 (bf16 pair).
// csr loads distributed across the 8 lanes, broadcast via __shfl.
__global__ __launch_bounds__(256) void k_agg1(const int* __restrict__ csr,
                                              const int* __restrict__ offs,
                                              const int* __restrict__ cnt,
                                              const float* __restrict__ dinv,
                                              const unsigned* __restrict__ hs1u,
                                              const float* __restrict__ b1,
                                              const float* __restrict__ W2,
                                              float* __restrict__ hs2p, int N) {
    int lane = threadIdx.x & 7;
    int i = blockIdx.x * 32 + (threadIdx.x >> 3);
    float w2a[NCLS], w2b[NCLS];
#pragma unroll
    for (int c = 0; c < NCLS; c++) {
        w2a[c] = W2[(2 * lane) * NCLS + c];
        w2b[c] = W2[(2 * lane + 1) * NCLS + c];
    }
    float b1a = b1[2 * lane], b1b = b1[2 * lane + 1];
    if (i >= N) return;  // group-uniform
    int start = offs[i], cn = cnt[i];
    unsigned su = hs1u[(size_t)i * 8 + lane];  // self-loop (pre-scaled)
    float accA = __uint_as_float(su << 16);
    float accB = __uint_as_float(su & 0xffff0000u);
    int full = cn & ~7;
    for (int k = 0; k < full; k += 8) {
        int ev = csr[start + k + lane];
#pragma unroll
        for (int t = 0; t < 8; ++t) {
            int s = __shfl(ev, t, 8);
            unsigned u = hs1u[(size_t)s * 8 + lane];
            accA += __uint_as_float(u << 16);
            accB += __uint_as_float(u & 0xffff0000u);
        }
    }
    int rem = cn - full;
    if (rem) {
        int ev = (lane < rem) ? csr[start + full + lane] : 0;
        for (int t = 0; t < rem; ++t) {
            int s = __shfl(ev, t, 8);
            unsigned u = hs1u[(size_t)s * 8 + lane];
            accA += __uint_as_float(u << 16);
            accB += __uint_as_float(u & 0xffff0000u);
        }
    }
    float dv = dinv[i];
    float vA = fmaf(dv, accA, b1a);
    float vB = fmaf(dv, accB, b1b);
    float hA = vA > 0.0f ? vA : 0.0f;
    float hB = vB > 0.0f ? vB : 0.0f;
    float res[NCLS];
#pragma unroll
    for (int c = 0; c < NCLS; c++) {
        float t = fmaf(hA, w2a[c], hB * w2b[c]);
#pragma unroll
        for (int w = 4; w >= 1; w >>= 1) t += __shfl_xor(t, w, 8);
        res[c] = t;
    }
    float o = res[0];
#pragma unroll
    for (int c = 1; c < NCLS; c++) o = (lane == c) ? res[c] : o;
    hs2p[(size_t)i * 8 + lane] = dv * o;  // lane 7 writes dv*res[0] (pad, unused)
}

// ---- AGG2: CSR gather (8 f32/row padded) + b2 + log_softmax -> out ----
// 8 lanes/node; csr loads distributed + __shfl broadcast; aligned 32B rows.
__global__ __launch_bounds__(256) void k_agg2(const int* __restrict__ csr,
                                              const int* __restrict__ offs,
                                              const int* __restrict__ cnt,
                                              const float* __restrict__ dinv,
                                              const float* __restrict__ hs2p,
                                              const float* __restrict__ b2,
                                              float* __restrict__ out, int N) {
    int lane = threadIdx.x & 7;
    int i = blockIdx.x * 32 + (threadIdx.x >> 3);
    if (i >= N) return;  // group-uniform
    int start = offs[i], cn = cnt[i];
    float acc = hs2p[(size_t)i * 8 + lane];  // self-loop (pre-scaled)
    int full = cn & ~7;
    for (int k = 0; k < full; k += 8) {
        int ev = csr[start + k + lane];
#pragma unroll
        for (int t = 0; t < 8; ++t) {
            int s = __shfl(ev, t, 8);
            acc += hs2p[(size_t)s * 8 + lane];
        }
    }
    int rem = cn - full;
    if (rem) {
        int ev = (lane < rem) ? csr[start + full + lane] : 0;
        for (int t = 0; t < rem; ++t) {
            int s = __shfl(ev, t, 8);
            acc += hs2p[(size_t)s * 8 + lane];
        }
    }
    int cc = lane < NCLS ? lane : NCLS - 1;
    float v = fmaf(dinv[i], acc, b2[cc]);
    float vm = (lane < NCLS) ? v : -INFINITY;
    float m = vm;
#pragma unroll
    for (int w = 4; w >= 1; w >>= 1) m = fmaxf(m, __shfl_xor(m, w, 8));
    float e = (lane < NCLS) ? expf(v - m) : 0.0f;
    float ssum = e;
#pragma unroll
    for (int w = 4; w >= 1; w >>= 1) ssum += __shfl_xor(ssum, w, 8);
    if (lane < NCLS) out[(size_t)i * NCLS + lane] = v - m - logf(ssum);
}

extern "C" void kernel_launch(void* const* d_in, const int* in_sizes, int n_in,
                              void* d_out, int out_size, void* d_ws, size_t ws_size,
                              hipStream_t stream) {
    const float* x  = (const float*)d_in[0];
    const int*   ei = (const int*)d_in[1];
    const float* W1 = (const float*)d_in[2];
    const float* b1 = (const float*)d_in[3];
    const float* W2 = (const float*)d_in[4];
    const float* b2 = (const float*)d_in[5];
    float* out = (float*)d_out;

    const int N = in_sizes[0] / F_IN;          // 100000
    const int E = in_sizes[1] / 2;             // 3200000
    const int nb = (N + BK - 1) / BK;          // 391
    const int perChunk = (E + NCHUNK - 1) / NCHUNK;  // 12500

    // ws layout in 4B words, 16B-aligned chunks:
    // [part E | hs2p 8N (aliased; part dead after k_b)][csr E][hs1b 8N(u32)]
    // [dinv N][cnt N][offs N][bh 256*nb][Tb nb][Bb nb]
    unsigned* w = (unsigned*)d_ws;
    auto al4 = [](size_t v) { return (v + 3) & ~(size_t)3; };
    size_t o = 0;
    unsigned*       part = w + o;
    float*          hs2p = (float*)(w + o);     o = al4(o + E);
    int*            csr  = (int*)(w + o);       o = al4(o + E);
    unsigned short* hs1b = (unsigned short*)(w + o); o = al4(o + (size_t)N * HID / 2);
    float*          dinv = (float*)(w + o);     o = al4(o + N);
    int*            cnt  = (int*)(w + o);       o = al4(o + N);
    int*            offs = (int*)(w + o);       o = al4(o + N);
    int*            bh   = (int*)(w + o);       o = al4(o + (size_t)NCHUNK * nb);
    int*            Tb   = (int*)(w + o);       o = al4(o + nb);
    int*            Bb   = (int*)(w + o);

    k_a1<<<NCHUNK, 256, 0, stream>>>(ei, E, perChunk, nb, bh);
    k_a2a<<<nb, 256, 0, stream>>>(bh, nb, Tb);
    k_a2b<<<1, 256, 0, stream>>>(Tb, nb, Bb);
    k_a3<<<NCHUNK, 256, 0, stream>>>(ei, E, perChunk, nb, bh, Bb, part);
    k_b<<<nb, 256, 0, stream>>>(part, Tb, Bb, csr, cnt, offs, dinv, N);
    k_gemm1<<<(N + 63) / 64, 256, 0, stream>>>(x, W1, dinv, hs1b, N);
    k_agg1<<<(N + 31) / 32, 256, 0, stream>>>(csr, offs, cnt, dinv,
                                              (const unsigned*)hs1b, b1, W2, hs2p, N);
    k_agg2<<<(N + 31) / 32, 256, 0, stream>>>(csr, offs, cnt, dinv, hs2p, b2, out, N);
}

// Round 4
// 448.532 us; speedup vs baseline: 1.1454x; 1.0152x over previous
//
#include <hip/hip_runtime.h>
#include <math.h>

// GCN 2-layer, f32 in/out. N=100000, E=3200000, F_in=512, H=16, C=7.
// Round 10: round-9 structure + software pipelining of the latency chains:
//   - k_gemm1: x-row loads issued BEFORE W1 staging (first-touch hidden);
//     p-loop hand-pipelined (#pragma unroll 1 + named prefetch regs) so 4
//     HBM loads are in flight under every FMA block
//   - k_agg1/k_agg2: next csr 8-edge batch prefetched before processing the
//     current one (csr padded +8 ints; over-read values never dereferenced)
//   - partition phase unchanged from round 9 (BK=256)

#define F_IN 512
#define HID  16
#define NCLS 7
#define NCHUNK 256
#define BK 256        // nodes per bucket
#define NBMAX 400     // >= nb = ceil(N/256) = 391
#define CAP 9216      // LDS edge capacity in k_b (mean 8192, +11 sigma)
#define WT_STRIDE 516 // padded k-stride of transposed W1 in LDS

static __device__ __forceinline__ float bf2f(unsigned short u) {
    union { unsigned int i; float f; } v; v.i = ((unsigned int)u) << 16; return v.f;
}
static __device__ __forceinline__ unsigned short f2bf(float f) {
    union { float f; unsigned int u; } v; v.f = f;
    unsigned int b = v.u;
    return (unsigned short)((b + 0x7FFFu + ((b >> 16) & 1u)) >> 16);  // RNE
}

// ---- A1: per-chunk histogram over buckets (dst>>8) ----
__global__ __launch_bounds__(256) void k_a1(const int* __restrict__ ei, int E, int perChunk,
                                            int nb, int* __restrict__ bh) {
    __shared__ int hist[NBMAX];
    for (int t = threadIdx.x; t < nb; t += 256) hist[t] = 0;
    __syncthreads();
    const int* dst = ei + E;
    int c = blockIdx.x;
    int s0 = c * perChunk;
    int s1 = min(s0 + perChunk, E);
    for (int e = s0 + threadIdx.x; e < s1; e += 256)
        atomicAdd(&hist[dst[e] >> 8], 1);
    __syncthreads();
    for (int t = threadIdx.x; t < nb; t += 256) bh[(size_t)c * nb + t] = hist[t];
}

// ---- A2a: per-bucket exclusive scan across the 256 chunks (in place) + total ----
__global__ __launch_bounds__(256) void k_a2a(int* __restrict__ bh, int nb,
                                             int* __restrict__ Tb) {
    __shared__ int sd[256];
    int b = blockIdx.x, tid = threadIdx.x;
    int v = bh[(size_t)tid * nb + b];
    sd[tid] = v;
    __syncthreads();
    for (int off = 1; off < 256; off <<= 1) {
        int t = (tid >= off) ? sd[tid - off] : 0;
        __syncthreads();
        sd[tid] += t;
        __syncthreads();
    }
    bh[(size_t)tid * nb + b] = sd[tid] - v;
    if (tid == 255) Tb[b] = sd[255];
}

// ---- A2b: exclusive scan of bucket totals -> bucket bases ----
__global__ __launch_bounds__(256) void k_a2b(const int* __restrict__ Tb, int nb,
                                             int* __restrict__ Bb) {
    __shared__ int sd[256];
    int tid = threadIdx.x;
    int carry = 0;
    for (int base = 0; base < nb; base += 256) {
        int v = (base + tid < nb) ? Tb[base + tid] : 0;
        sd[tid] = v;
        __syncthreads();
        for (int off = 1; off < 256; off <<= 1) {
            int t = (tid >= off) ? sd[tid - off] : 0;
            __syncthreads();
            sd[tid] += t;
            __syncthreads();
        }
        if (base + tid < nb) Bb[base + tid] = carry + sd[tid] - v;
        carry += sd[255];
        __syncthreads();
    }
}

// ---- A3: deterministic partition scatter, packed (dl<<20)|src ----
__global__ __launch_bounds__(256) void k_a3(const int* __restrict__ ei, int E, int perChunk,
                                            int nb, const int* __restrict__ bh,
                                            const int* __restrict__ Bb,
                                            unsigned* __restrict__ part) {
    __shared__ int cur[NBMAX];
    __shared__ int baseL[NBMAX];
    int c = blockIdx.x;
    for (int t = threadIdx.x; t < nb; t += 256) {
        cur[t] = 0;
        baseL[t] = Bb[t] + bh[(size_t)c * nb + t];
    }
    __syncthreads();
    const int* src = ei;
    const int* dst = ei + E;
    int s0 = c * perChunk;
    int s1 = min(s0 + perChunk, E);
    for (int e = s0 + threadIdx.x; e < s1; e += 256) {
        int s = src[e], d = dst[e];
        int b = d >> 8;
        int r = atomicAdd(&cur[b], 1);
        part[baseL[b] + r] = ((unsigned)(d & (BK - 1)) << 20) | (unsigned)s;
    }
}

// ---- B: per-bucket counting sort -> csr (sorted by dst), cnt, offs, dinv ----
__global__ __launch_bounds__(256) void k_b(const unsigned* __restrict__ part,
                                           const int* __restrict__ Tb,
                                           const int* __restrict__ Bb,
                                           int* __restrict__ csr, int* __restrict__ cnt,
                                           int* __restrict__ offs, float* __restrict__ dinv,
                                           int N) {
    __shared__ unsigned eL[CAP];
    __shared__ int hist[BK], sd[BK], cur[BK];
    int b = blockIdx.x, tid = threadIdx.x;
    int base = Bb[b], ct = Tb[b];
    hist[tid] = 0;
    __syncthreads();
    for (int k = tid; k < ct; k += 256) {
        unsigned v = part[base + k];
        if (k < CAP) eL[k] = v;
        atomicAdd(&hist[v >> 20], 1);
    }
    __syncthreads();
    sd[tid] = hist[tid];
    __syncthreads();
    for (int off = 1; off < BK; off <<= 1) {
        int t = (tid >= off) ? sd[tid - off] : 0;
        __syncthreads();
        sd[tid] += t;
        __syncthreads();
    }
    {
        int h = hist[tid];
        int ex = sd[tid] - h;
        cur[tid] = ex;
        int node = b * BK + tid;
        if (node < N) {
            cnt[node] = h;
            offs[node] = base + ex;
            dinv[node] = rsqrtf((float)h + 1.0f);
        }
    }
    __syncthreads();
    for (int k = tid; k < ct; k += 256) {
        unsigned v = (k < CAP) ? eL[k] : part[base + k];
        int dl = (int)(v >> 20);
        int r = atomicAdd(&cur[dl], 1);
        csr[base + r] = (int)(v & 0xFFFFFu);
    }
}

// ---- GEMM1: hs1b[i][:] = bf16( dinv[i] * (x[i,:] @ W1) ) ----
// 16 lanes/row, 4 rows per lane-group (k split across lanes, W reused 4x).
// W1 staged transposed in LDS; x loads software-pipelined 1-deep so 4 HBM
// loads are always in flight under each FMA block.
__global__ __launch_bounds__(256) void k_gemm1(const float* __restrict__ x,
                                               const float* __restrict__ W1,
                                               const float* __restrict__ dinv,
                                               unsigned short* __restrict__ hs1b,
                                               int N) {
    __shared__ float wlT[HID * WT_STRIDE];  // 33 KB

    int lane = threadIdx.x & 15;
    int g = threadIdx.x >> 4;                 // lane-group 0..15
    int rbase = blockIdx.x * 64 + g * 4;      // 4 rows per group

    const float* xp0 = x + (size_t)(rbase + 0 < N ? rbase + 0 : 0) * F_IN + 4 * lane;
    const float* xp1 = x + (size_t)(rbase + 1 < N ? rbase + 1 : 0) * F_IN + 4 * lane;
    const float* xp2 = x + (size_t)(rbase + 2 < N ? rbase + 2 : 0) * F_IN + 4 * lane;
    const float* xp3 = x + (size_t)(rbase + 3 < N ? rbase + 3 : 0) * F_IN + 4 * lane;

    // issue first x loads BEFORE staging: latency hidden under W1 stage
    float4 a0 = *(const float4*)(xp0);
    float4 a1 = *(const float4*)(xp1);
    float4 a2 = *(const float4*)(xp2);
    float4 a3 = *(const float4*)(xp3);

    {
        int j = threadIdx.x & 15;
        int k0 = threadIdx.x >> 4;
        for (int it = 0; it < F_IN / 16; ++it) {
            int k = k0 + 16 * it;
            wlT[j * WT_STRIDE + k] = W1[k * HID + j];
        }
    }
    __syncthreads();

    float acc[4][16];
#pragma unroll
    for (int r = 0; r < 4; ++r)
#pragma unroll
        for (int j = 0; j < 16; ++j) acc[r][j] = 0.0f;

    auto fma_block = [&](int p, const float4& A0, const float4& A1,
                         const float4& A2, const float4& A3) {
        const float* wb = &wlT[64 * p + 4 * lane];
#pragma unroll
        for (int j = 0; j < 16; ++j) {
            float4 w4 = *(const float4*)(wb + (size_t)j * WT_STRIDE);
            acc[0][j] = fmaf(A0.x, w4.x, fmaf(A0.y, w4.y, fmaf(A0.z, w4.z, fmaf(A0.w, w4.w, acc[0][j]))));
            acc[1][j] = fmaf(A1.x, w4.x, fmaf(A1.y, w4.y, fmaf(A1.z, w4.z, fmaf(A1.w, w4.w, acc[1][j]))));
            acc[2][j] = fmaf(A2.x, w4.x, fmaf(A2.y, w4.y, fmaf(A2.z, w4.z, fmaf(A2.w, w4.w, acc[2][j]))));
            acc[3][j] = fmaf(A3.x, w4.x, fmaf(A3.y, w4.y, fmaf(A3.z, w4.z, fmaf(A3.w, w4.w, acc[3][j]))));
        }
    };

#pragma unroll 1
    for (int p = 0; p < 7; ++p) {
        float4 n0 = *(const float4*)(xp0 + 64 * (p + 1));
        float4 n1 = *(const float4*)(xp1 + 64 * (p + 1));
        float4 n2 = *(const float4*)(xp2 + 64 * (p + 1));
        float4 n3 = *(const float4*)(xp3 + 64 * (p + 1));
        fma_block(p, a0, a1, a2, a3);
        a0 = n0; a1 = n1; a2 = n2; a3 = n3;
    }
    fma_block(7, a0, a1, a2, a3);

    // reduce-and-transpose across the 16 lanes: lane l ends with feature j=l.
    bool b8 = (lane & 8) != 0, b4 = (lane & 4) != 0, b2 = (lane & 2) != 0, b1 = (lane & 1) != 0;
#pragma unroll
    for (int r = 0; r < 4; ++r) {
#pragma unroll
        for (int j = 0; j < 8; ++j) {
            float lo = acc[r][j], hi = acc[r][j + 8];
            float keep = b8 ? hi : lo;
            float send = b8 ? lo : hi;
            acc[r][j] = keep + __shfl_xor(send, 8, 16);
        }
#pragma unroll
        for (int j = 0; j < 4; ++j) {
            float lo = acc[r][j], hi = acc[r][j + 4];
            float keep = b4 ? hi : lo;
            float send = b4 ? lo : hi;
            acc[r][j] = keep + __shfl_xor(send, 4, 16);
        }
#pragma unroll
        for (int j = 0; j < 2; ++j) {
            float lo = acc[r][j], hi = acc[r][j + 2];
            float keep = b2 ? hi : lo;
            float send = b2 ? lo : hi;
            acc[r][j] = keep + __shfl_xor(send, 2, 16);
        }
        {
            float lo = acc[r][0], hi = acc[r][1];
            float keep = b1 ? hi : lo;
            float send = b1 ? lo : hi;
            acc[r][0] = keep + __shfl_xor(send, 1, 16);
        }
        int row = rbase + r;
        if (row < N)
            hs1b[(size_t)row * HID + lane] = f2bf(dinv[row] * acc[r][0]);
    }
}

// ---- AGG1: CSR gather + b1 + relu + @W2 + *dinv -> hs2p (f32, 8/row) ----
// 8 lanes/node, lane owns features (2l,2l+1) as one u32 (bf16 pair).
// csr batches prefetched 1-deep (padded over-read, values never dereferenced).
__global__ __launch_bounds__(256) void k_agg1(const int* __restrict__ csr,
                                              const int* __restrict__ offs,
                                              const int* __restrict__ cnt,
                                              const float* __restrict__ dinv,
                                              const unsigned* __restrict__ hs1u,
                                              const float* __restrict__ b1,
                                              const float* __restrict__ W2,
                                              float* __restrict__ hs2p, int N) {
    int lane = threadIdx.x & 7;
    int i = blockIdx.x * 32 + (threadIdx.x >> 3);
    float w2a[NCLS], w2b[NCLS];
#pragma unroll
    for (int c = 0; c < NCLS; c++) {
        w2a[c] = W2[(2 * lane) * NCLS + c];
        w2b[c] = W2[(2 * lane + 1) * NCLS + c];
    }
    float b1a = b1[2 * lane], b1b = b1[2 * lane + 1];
    if (i >= N) return;  // group-uniform
    int start = offs[i], cn = cnt[i];
    unsigned su = hs1u[(size_t)i * 8 + lane];  // self-loop (pre-scaled)
    float accA = __uint_as_float(su << 16);
    float accB = __uint_as_float(su & 0xffff0000u);
    int full = cn & ~7;
    int rem = cn - full;
    int evn = csr[start + lane];               // padded: safe over-read
    for (int k = 0; k < full; k += 8) {
        int ev = evn;
        evn = csr[start + k + 8 + lane];       // prefetch next batch
#pragma unroll
        for (int t = 0; t < 8; ++t) {
            int s = __shfl(ev, t, 8);
            unsigned u = hs1u[(size_t)s * 8 + lane];
            accA += __uint_as_float(u << 16);
            accB += __uint_as_float(u & 0xffff0000u);
        }
    }
    for (int t = 0; t < rem; ++t) {
        int s = __shfl(evn, t, 8);
        unsigned u = hs1u[(size_t)s * 8 + lane];
        accA += __uint_as_float(u << 16);
        accB += __uint_as_float(u & 0xffff0000u);
    }
    float dv = dinv[i];
    float vA = fmaf(dv, accA, b1a);
    float vB = fmaf(dv, accB, b1b);
    float hA = vA > 0.0f ? vA : 0.0f;
    float hB = vB > 0.0f ? vB : 0.0f;
    float res[NCLS];
#pragma unroll
    for (int c = 0; c < NCLS; c++) {
        float t = fmaf(hA, w2a[c], hB * w2b[c]);
#pragma unroll
        for (int w = 4; w >= 1; w >>= 1) t += __shfl_xor(t, w, 8);
        res[c] = t;
    }
    float o = res[0];
#pragma unroll
    for (int c = 1; c < NCLS; c++) o = (lane == c) ? res[c] : o;
    hs2p[(size_t)i * 8 + lane] = dv * o;  // lane 7 writes dv*res[0] (pad, unused)
}

// ---- AGG2: CSR gather (8 f32/row padded) + b2 + log_softmax -> out ----
// 8 lanes/node; csr batches prefetched 1-deep; aligned 32B rows.
__global__ __launch_bounds__(256) void k_agg2(const int* __restrict__ csr,
                                              const int* __restrict__ offs,
                                              const int* __restrict__ cnt,
                                              const float* __restrict__ dinv,
                                              const float* __restrict__ hs2p,
                                              const float* __restrict__ b2,
                                              float* __restrict__ out, int N) {
    int lane = threadIdx.x & 7;
    int i = blockIdx.x * 32 + (threadIdx.x >> 3);
    if (i >= N) return;  // group-uniform
    int start = offs[i], cn = cnt[i];
    float acc = hs2p[(size_t)i * 8 + lane];  // self-loop (pre-scaled)
    int full = cn & ~7;
    int rem = cn - full;
    int evn = csr[start + lane];             // padded: safe over-read
    for (int k = 0; k < full; k += 8) {
        int ev = evn;
        evn = csr[start + k + 8 + lane];     // prefetch next batch
#pragma unroll
        for (int t = 0; t < 8; ++t) {
            int s = __shfl(ev, t, 8);
            acc += hs2p[(size_t)s * 8 + lane];
        }
    }
    for (int t = 0; t < rem; ++t) {
        int s = __shfl(evn, t, 8);
        acc += hs2p[(size_t)s * 8 + lane];
    }
    int cc = lane < NCLS ? lane : NCLS - 1;
    float v = fmaf(dinv[i], acc, b2[cc]);
    float vm = (lane < NCLS) ? v : -INFINITY;
    float m = vm;
#pragma unroll
    for (int w = 4; w >= 1; w >>= 1) m = fmaxf(m, __shfl_xor(m, w, 8));
    float e = (lane < NCLS) ? expf(v - m) : 0.0f;
    float ssum = e;
#pragma unroll
    for (int w = 4; w >= 1; w >>= 1) ssum += __shfl_xor(ssum, w, 8);
    if (lane < NCLS) out[(size_t)i * NCLS + lane] = v - m - logf(ssum);
}

extern "C" void kernel_launch(void* const* d_in, const int* in_sizes, int n_in,
                              void* d_out, int out_size, void* d_ws, size_t ws_size,
                              hipStream_t stream) {
    const float* x  = (const float*)d_in[0];
    const int*   ei = (const int*)d_in[1];
    const float* W1 = (const float*)d_in[2];
    const float* b1 = (const float*)d_in[3];
    const float* W2 = (const float*)d_in[4];
    const float* b2 = (const float*)d_in[5];
    float* out = (float*)d_out;

    const int N = in_sizes[0] / F_IN;          // 100000
    const int E = in_sizes[1] / 2;             // 3200000
    const int nb = (N + BK - 1) / BK;          // 391
    const int perChunk = (E + NCHUNK - 1) / NCHUNK;  // 12500

    // ws layout in 4B words, 16B-aligned chunks:
    // [part E | hs2p 8N (aliased; part dead after k_b)][csr E+16][hs1b 8N(u32)]
    // [dinv N][cnt N][offs N][bh 256*nb][Tb nb][Bb nb]
    unsigned* w = (unsigned*)d_ws;
    auto al4 = [](size_t v) { return (v + 3) & ~(size_t)3; };
    size_t o = 0;
    unsigned*       part = w + o;
    float*          hs2p = (float*)(w + o);     o = al4(o + E);
    int*            csr  = (int*)(w + o);       o = al4(o + E + 16);
    unsigned short* hs1b = (unsigned short*)(w + o); o = al4(o + (size_t)N * HID / 2);
    float*          dinv = (float*)(w + o);     o = al4(o + N);
    int*            cnt  = (int*)(w + o);       o = al4(o + N);
    int*            offs = (int*)(w + o);       o = al4(o + N);
    int*            bh   = (int*)(w + o);       o = al4(o + (size_t)NCHUNK * nb);
    int*            Tb   = (int*)(w + o);       o = al4(o + nb);
    int*            Bb   = (int*)(w + o);

    k_a1<<<NCHUNK, 256, 0, stream>>>(ei, E, perChunk, nb, bh);
    k_a2a<<<nb, 256, 0, stream>>>(bh, nb, Tb);
    k_a2b<<<1, 256, 0, stream>>>(Tb, nb, Bb);
    k_a3<<<NCHUNK, 256, 0, stream>>>(ei, E, perChunk, nb, bh, Bb, part);
    k_b<<<nb, 256, 0, stream>>>(part, Tb, Bb, csr, cnt, offs, dinv, N);
    k_gemm1<<<(N + 63) / 64, 256, 0, stream>>>(x, W1, dinv, hs1b, N);
    k_agg1<<<(N + 31) / 32, 256, 0, stream>>>(csr, offs, cnt, dinv,
                                              (const unsigned*)hs1b, b1, W2, hs2p, N);
    k_agg2<<<(N + 31) / 32, 256, 0, stream>>>(csr, offs, cnt, dinv, hs2p, b2, out, N);
}